// Round 4
// baseline (928.015 us; speedup 1.0000x reference)
//
#include <hip/hip_runtime.h>

#define NGR 4096
#define NPG 24
#define EPG 48
#define LPG 144
#define NITER 4
#define HID 128
#define NN (NGR*NPG)
#define NE (NGR*EPG)
#define NL (NGR*LPG)

typedef unsigned int uint;
typedef unsigned short ushort;
typedef short bf16x8 __attribute__((ext_vector_type(8)));
typedef float f32x4 __attribute__((ext_vector_type(4)));
typedef float f32x2 __attribute__((ext_vector_type(2)));

__device__ __forceinline__ float b2f(ushort u){ return __uint_as_float(((uint)u)<<16); }
__device__ __forceinline__ float b2f_lo(uint u){ return __uint_as_float(u<<16); }
__device__ __forceinline__ float b2f_hi(uint u){ return __uint_as_float(u & 0xFFFF0000u); }
__device__ __forceinline__ ushort f2b(float f){
  uint x = __float_as_uint(f);
  x += 0x7FFFu + ((x>>16)&1u);
  return (ushort)(x>>16);
}
__device__ __forceinline__ ushort f2b_lo(float v){   // lo part of bf16x2 split
  ushort hi = f2b(v);
  return f2b(v - b2f(hi));
}
__device__ __forceinline__ float wredsum(float v){
  #pragma unroll
  for(int m=32;m;m>>=1) v += __shfl_xor(v, m, 64);
  return v;
}
__device__ __forceinline__ f32x4 mfma16(bf16x8 a, bf16x8 b, f32x4 c){
  return __builtin_amdgcn_mfma_f32_16x16x32_bf16(a, b, c, 0, 0, 0);
}

// ---------------------------------------------------------------------------
// K1: h = x@w_mlp + b (bf16x3 MFMA) ; hu = h@w_u ; hv = h@w_v (bf16x3)
// fp32-equivalent precision: A = A_hi + A_lo, W = W_hi + W_lo,
// acc = Ah*Wh + Al*Wh + Ah*Wl  (lo*lo dropped, ~2^-16).
// ---------------------------------------------------------------------------
__global__ __launch_bounds__(256) void k_feat(
    const float* __restrict__ x, const float* __restrict__ wmlp, const float* __restrict__ bmlp,
    const float* __restrict__ wu, const float* __restrict__ wvv,
    ushort* __restrict__ h, float* __restrict__ hu, float* __restrict__ hv)
{
  __shared__ __align__(16) ushort lds[26624];   // 53248 B
  // GEMM1 layout (stride 104): Ah[0..6656) Al[6656..13312) Wt[13312..26624)
  ushort* Ah = lds;
  ushort* Al = lds + 6656;
  ushort* Wt = lds + 13312;
  // GEMM2 layout (stride 136): Ah2[0..8704) Al2[8704..17408) Wt2[17408..26112)
  ushort* Ah2 = lds;
  ushort* Al2 = lds + 8704;
  ushort* Wt2 = lds + 17408;

  const int tid = threadIdx.x;
  const int lane = tid & 63, wid = tid >> 6;
  const int quad = lane >> 4, ln = lane & 15;
  const int n0 = blockIdx.x * 64;
  const int mrow = wid*16 + ln;
  const f32x4 z4 = {0.f,0.f,0.f,0.f};

  // ---- GEMM1 staging: x split, wmlp hi ----
  for(int idx=tid; idx<64*70; idx+=256){ int r=idx/70, cc=idx-r*70;
    float v = x[(size_t)(n0+r)*70+cc]; ushort hi=f2b(v);
    Ah[r*104+cc]=hi; Al[r*104+cc]=f2b(v-b2f(hi)); }
  for(int idx=tid; idx<64*34; idx+=256){ int r=idx/34, o=idx-r*34;
    Ah[r*104+70+o]=0; Al[r*104+70+o]=0; }
  for(int idx=tid; idx<70*128; idx+=256){ int k=idx>>7, n=idx&127; Wt[n*104+k]=f2b(wmlp[idx]); }
  for(int idx=tid; idx<128*34; idx+=256){ int n=idx/34, o=idx-n*34; Wt[n*104+70+o]=0; }
  __syncthreads();

  f32x4 acc[8];
  #pragma unroll
  for(int s=0;s<8;s++) acc[s]=z4;
  // phase W_hi: Ah*Wh + Al*Wh
  #pragma unroll
  for(int ks=0; ks<3; ks++){
    const int ko = ks*32 + quad*8;
    bf16x8 ah = *(const bf16x8*)&Ah[mrow*104 + ko];
    bf16x8 al = *(const bf16x8*)&Al[mrow*104 + ko];
    #pragma unroll
    for(int s=0;s<8;s++){
      bf16x8 bf = *(const bf16x8*)&Wt[(s*16+ln)*104 + ko];
      acc[s] = mfma16(ah, bf, acc[s]);
      acc[s] = mfma16(al, bf, acc[s]);
    }
  }
  __syncthreads();
  // restage W lo
  for(int idx=tid; idx<70*128; idx+=256){ int k=idx>>7, n=idx&127; Wt[n*104+k]=f2b_lo(wmlp[idx]); }
  __syncthreads();
  // phase W_lo: Ah*Wl
  #pragma unroll
  for(int ks=0; ks<3; ks++){
    const int ko = ks*32 + quad*8;
    bf16x8 ah = *(const bf16x8*)&Ah[mrow*104 + ko];
    #pragma unroll
    for(int s=0;s<8;s++){
      bf16x8 bf = *(const bf16x8*)&Wt[(s*16+ln)*104 + ko];
      acc[s] = mfma16(ah, bf, acc[s]);
    }
  }
  __syncthreads();   // A/W regions about to be overwritten with stride-136 layout

  // ---- h = acc + bias: global bf16 + split into Ah2/Al2 ----
  #pragma unroll
  for(int s=0;s<8;s++){
    float bb = bmlp[s*16+ln];
    #pragma unroll
    for(int r=0;r<4;r++){
      float hval = acc[s][r] + bb;
      int row = wid*16+quad*4+r, col = s*16+ln;
      ushort hi = f2b(hval);
      h[(size_t)(n0+row)*128 + col] = hi;
      Ah2[row*136+col] = hi;
      Al2[row*136+col] = f2b(hval - b2f(hi));
    }
  }
  __syncthreads();

  // ---- GEMM2/3: hu = h@wu, hv = h@wv, in 64-col halves, bf16x3 ----
  for(int w=0; w<2; w++){
    const float* wsp = w ? wvv : wu;
    float* dst = w ? hv : hu;
    for(int half=0; half<2; half++){
      for(int idx=tid; idx<64*128; idx+=256){ int n=idx>>7, k=idx&127;
        Wt2[n*136+k]=f2b(wsp[k*128 + half*64 + n]); }
      __syncthreads();
      f32x4 a2[4];
      #pragma unroll
      for(int s=0;s<4;s++) a2[s]=z4;
      #pragma unroll
      for(int ks=0;ks<4;ks++){
        const int ko = ks*32 + quad*8;
        bf16x8 ah = *(const bf16x8*)&Ah2[mrow*136 + ko];
        bf16x8 al = *(const bf16x8*)&Al2[mrow*136 + ko];
        #pragma unroll
        for(int s=0;s<4;s++){
          bf16x8 bf = *(const bf16x8*)&Wt2[(s*16+ln)*136 + ko];
          a2[s] = mfma16(ah, bf, a2[s]);
          a2[s] = mfma16(al, bf, a2[s]);
        }
      }
      __syncthreads();
      for(int idx=tid; idx<64*128; idx+=256){ int n=idx>>7, k=idx&127;
        Wt2[n*136+k]=f2b_lo(wsp[k*128 + half*64 + n]); }
      __syncthreads();
      #pragma unroll
      for(int ks=0;ks<4;ks++){
        const int ko = ks*32 + quad*8;
        bf16x8 ah = *(const bf16x8*)&Ah2[mrow*136 + ko];
        #pragma unroll
        for(int s=0;s<4;s++){
          bf16x8 bf = *(const bf16x8*)&Wt2[(s*16+ln)*136 + ko];
          a2[s] = mfma16(ah, bf, a2[s]);
        }
      }
      __syncthreads();   // before next half restages Wt2
      #pragma unroll
      for(int s=0;s<4;s++)
        #pragma unroll
        for(int r=0;r<4;r++)
          dst[(size_t)(n0+wid*16+quad*4+r)*128 + half*64 + s*16+ln] = a2[s][r];
    }
  }
}

// ---------------------------------------------------------------------------
// K2: one workgroup per graph. fp32 recursion in LDS ping-pong; two-pass
// temporal weighted sum. z written fp32.
// ---------------------------------------------------------------------------
__global__ __launch_bounds__(256) void k_graph(
  const float* __restrict__ hu, const float* __restrict__ hv,
  const ushort* __restrict__ h, const float* __restrict__ ea,
  const int* __restrict__ eidx, const int* __restrict__ lidx,
  const float* __restrict__ wedge, const float* __restrict__ wrel, const float* __restrict__ brel,
  const float* __restrict__ wroot, const float* __restrict__ aatt, const float* __restrict__ abias,
  const float* __restrict__ wgout, const float* __restrict__ bgout,
  float* __restrict__ z)
{
  const int g = blockIdx.x;
  const int tid = threadIdx.x;
  const int lane = tid & 63, wid = tid >> 6;
  const int c = lane;                  // feature pair (2c, 2c+1)
  const int E0 = g*EPG, L0 = g*LPG;

  __shared__ __align__(16) float buf[2][EPG*HID];  // fp32 ping-pong out_t (49152 B)
  __shared__ float gtmp[HID];
  __shared__ float gsf[NITER][HID];
  __shared__ ushort csr_src[LPG];
  __shared__ ushort rstart[EPG+1];
  __shared__ uint  cnt[EPG];
  __shared__ ushort dstl[EPG];
  __shared__ float p_sh[EPG], r_sh[EPG], xc[EPG];
  __shared__ float score[NITER], wts[NITER];

  float we0[6], we1[6];
  #pragma unroll
  for(int k=0;k<6;k++){ we0[k]=wedge[k*128 + 2*c]; we1[k]=wedge[k*128 + 2*c+1]; }
  const float wr0 = wrel[2*c],  wr1 = wrel[2*c+1];
  const float wo0 = wroot[2*c], wo1 = wroot[2*c+1];
  const float brel_f = brel[0];

  // ---- CSR of line-graph in-edges ----
  if(tid < EPG){ cnt[tid]=0u; dstl[tid] = (ushort)(eidx[NE + E0 + tid] - g*NPG); }
  __syncthreads();
  int myld=0, myls=0;
  if(tid < LPG){ myls = lidx[L0+tid] - E0; myld = lidx[NL + L0 + tid] - E0;
                 atomicAdd(&cnt[myld], 1u); }
  __syncthreads();
  if(tid==0){ uint s=0; for(int i=0;i<EPG;i++){ rstart[i]=(ushort)s; s+=cnt[i]; } rstart[EPG]=(ushort)s; }
  __syncthreads();
  if(tid < EPG) cnt[tid]=0u;
  __syncthreads();
  if(tid < LPG){ uint slot = (uint)rstart[myld] + atomicAdd(&cnt[myld],1u); csr_src[slot]=(ushort)myls; }

  // ---- e0 (fp32, registers) ; buf[0] = e0 ----
  f32x2 e0r[12];
  #pragma unroll
  for(int ii=0; ii<12; ii++){
    int i = wid*12+ii, e = E0+i;
    int sg = eidx[e], dg = eidx[NE + e];
    f32x2 du = ((const f32x2*)hu)[sg*64 + c];
    f32x2 dv = ((const f32x2*)hv)[dg*64 + c];
    float a0 = du.x + dv.x, a1 = du.y + dv.y;
    #pragma unroll
    for(int k=0;k<6;k++){ float ev = ea[e*6+k]; a0 += ev*we0[k]; a1 += ev*we1[k]; }
    e0r[ii].x = a0*(1.f/3.f); e0r[ii].y = a1*(1.f/3.f);
    ((f32x2*)buf[0])[i*64 + c] = e0r[ii];
  }
  __syncthreads();

  // ---- Pass A: recursion + attention-pool scores ----
  for(int t=0; t<NITER; t++){
    const f32x2* prev = (const f32x2*)buf[t&1];
    f32x2* cur = (f32x2*)buf[(t+1)&1];
    if(tid<HID) gtmp[tid]=0.f;
    #pragma unroll
    for(int ii=0; ii<12; ii++){
      int i = wid*12+ii;
      float a0 = e0r[ii].x, a1 = e0r[ii].y;
      int js = rstart[i], je = rstart[i+1];
      for(int j=js;j<je;j++){
        f32x2 d = prev[(int)csr_src[j]*64 + c];
        a0 += d.x; a1 += d.y;
      }
      f32x2 o; o.x=a0; o.y=a1;
      cur[i*64+c] = o;
      float pv = a0*wr0 + a1*wr1;     // out . w_rel  (folds aggr@w_rel)
      float rv = a0*wo0 + a1*wo1;     // out . w_root
      pv = wredsum(pv); rv = wredsum(rv);
      if(lane==0){ p_sh[i]=pv; r_sh[i]=rv; }
    }
    __syncthreads();
    if(tid < EPG){
      float v = r_sh[tid] + brel_f;
      for(int j=rstart[tid]; j<rstart[tid+1]; j++) v += p_sh[csr_src[j]];
      xc[tid] = v;
    }
    __syncthreads();
    if(wid==0){
      float v = (lane<EPG) ? xc[lane] : -3.0e38f;
      float m = v;
      #pragma unroll
      for(int msk=32;msk;msk>>=1) m = fmaxf(m, __shfl_xor(m,msk,64));
      float e2 = (lane<EPG) ? __expf(v-m) : 0.f;
      float ssum = e2;
      #pragma unroll
      for(int msk=32;msk;msk>>=1) ssum += __shfl_xor(ssum,msk,64);
      if(lane<EPG) xc[lane] = e2/ssum;
    }
    __syncthreads();
    float gp0=0.f, gp1=0.f;
    #pragma unroll
    for(int ii=0; ii<12; ii++){
      int i = wid*12+ii;
      float sc = xc[i];
      f32x2 d = cur[i*64+c];
      gp0 += d.x*sc; gp1 += d.y*sc;
    }
    atomicAdd(&gtmp[2*c],   gp0);
    atomicAdd(&gtmp[2*c+1], gp1);
    __syncthreads();
    if(tid<HID) gsf[t][tid] = gtmp[tid];
    __syncthreads();
  }

  // ---- temporal attention: wave t computes score[t] ----
  {
    const int t = wid;
    float s0 = bgout[2*c], s1 = bgout[2*c+1];
    for(int k=0;k<128;k++){
      float gk = gsf[t][k];
      s0 += gk*wgout[k*128 + 2*c];
      s1 += gk*wgout[k*128 + 2*c+1];
    }
    float v = tanhf(s0)*aatt[(2*c)*4 + t] + tanhf(s1)*aatt[(2*c+1)*4 + t];
    v = wredsum(v);
    if(lane==0) score[t] = v + abias[t];
  }
  __syncthreads();
  if(tid==0){
    float m = fmaxf(fmaxf(score[0],score[1]), fmaxf(score[2],score[3]));
    float e0=__expf(score[0]-m), e1=__expf(score[1]-m), e2=__expf(score[2]-m), e3=__expf(score[3]-m);
    float s = e0+e1+e2+e3;
    wts[0]=e0/s; wts[1]=e1/s; wts[2]=e2/s; wts[3]=e3/s;
  }
  __syncthreads();

  // ---- Pass B: recompute recursion, accumulate weighted temporal sum ----
  f32x2 wacc[12];
  #pragma unroll
  for(int ii=0; ii<12; ii++){
    int i = wid*12+ii;
    ((f32x2*)buf[0])[i*64 + c] = e0r[ii];
    wacc[ii].x = 0.f; wacc[ii].y = 0.f;
  }
  __syncthreads();
  for(int t=0; t<NITER; t++){
    const f32x2* prev = (const f32x2*)buf[t&1];
    f32x2* cur = (f32x2*)buf[(t+1)&1];
    float w = wts[t];
    #pragma unroll
    for(int ii=0; ii<12; ii++){
      int i = wid*12+ii;
      float a0 = e0r[ii].x, a1 = e0r[ii].y;
      int js = rstart[i], je = rstart[i+1];
      for(int j=js;j<je;j++){
        f32x2 d = prev[(int)csr_src[j]*64 + c];
        a0 += d.x; a1 += d.y;
      }
      f32x2 o; o.x=a0; o.y=a1;
      cur[i*64+c] = o;
      wacc[ii].x += w*a0; wacc[ii].y += w*a1;
    }
    __syncthreads();
  }

  // ---- scatter to dst nodes, z = h + nacc (fp32) ----
  float* nacc = (float*)buf[0];
  for(int idx=tid; idx<NPG*HID; idx+=256) nacc[idx]=0.f;
  __syncthreads();
  #pragma unroll
  for(int ii=0; ii<12; ii++){
    int i = wid*12+ii;
    int dn = dstl[i];
    atomicAdd(&nacc[dn*128 + 2*c],   wacc[ii].x);
    atomicAdd(&nacc[dn*128 + 2*c+1], wacc[ii].y);
  }
  __syncthreads();
  for(int idx=tid; idx<NPG*64; idx+=256){
    int n = idx>>6, cc = idx&63;
    uint hh = ((const uint*)h)[(g*NPG+n)*64 + cc];
    f32x2 zo;
    zo.x = b2f_lo(hh) + nacc[n*128 + 2*cc];
    zo.y = b2f_hi(hh) + nacc[n*128 + 2*cc+1];
    ((f32x2*)z)[(g*NPG+n)*64 + cc] = zo;
  }
}

// ---------------------------------------------------------------------------
// K3: out = z @ w_block + b_block  (bf16x3 MFMA, fp32 in/out)
// ---------------------------------------------------------------------------
__global__ __launch_bounds__(256) void k_final(
    const float* __restrict__ zf, const float* __restrict__ wb, const float* __restrict__ bb,
    float* __restrict__ out)
{
  __shared__ __align__(16) ushort lds[26112];  // Ah[0..8704) Al[8704..17408) Wt[17408..26112)
  ushort* Ah = lds;
  ushort* Al = lds + 8704;
  ushort* Wt = lds + 17408;
  const int tid = threadIdx.x;
  const int lane = tid & 63, wid = tid >> 6;
  const int quad = lane >> 4, ln = lane & 15;
  const int n0 = blockIdx.x * 64;
  const int mrow = wid*16 + ln;
  const f32x4 z4 = {0.f,0.f,0.f,0.f};

  for(int idx=tid; idx<64*128; idx+=256){ int r=idx>>7, k=idx&127;
    float v = zf[(size_t)(n0+r)*128+k]; ushort hi=f2b(v);
    Ah[r*136+k]=hi; Al[r*136+k]=f2b(v-b2f(hi)); }
  __syncthreads();

  for(int half=0; half<2; half++){
    for(int idx=tid; idx<64*128; idx+=256){ int n=idx>>7, k=idx&127;
      Wt[n*136+k]=f2b(wb[k*128 + half*64 + n]); }
    __syncthreads();
    f32x4 a2[4];
    #pragma unroll
    for(int s=0;s<4;s++) a2[s]=z4;
    #pragma unroll
    for(int ks=0;ks<4;ks++){
      const int ko = ks*32 + quad*8;
      bf16x8 ah = *(const bf16x8*)&Ah[mrow*136 + ko];
      bf16x8 al = *(const bf16x8*)&Al[mrow*136 + ko];
      #pragma unroll
      for(int s=0;s<4;s++){
        bf16x8 bf = *(const bf16x8*)&Wt[(s*16+ln)*136 + ko];
        a2[s] = mfma16(ah, bf, a2[s]);
        a2[s] = mfma16(al, bf, a2[s]);
      }
    }
    __syncthreads();
    for(int idx=tid; idx<64*128; idx+=256){ int n=idx>>7, k=idx&127;
      Wt[n*136+k]=f2b_lo(wb[k*128 + half*64 + n]); }
    __syncthreads();
    #pragma unroll
    for(int ks=0;ks<4;ks++){
      const int ko = ks*32 + quad*8;
      bf16x8 ah = *(const bf16x8*)&Ah[mrow*136 + ko];
      #pragma unroll
      for(int s=0;s<4;s++){
        bf16x8 bf = *(const bf16x8*)&Wt[(s*16+ln)*136 + ko];
        a2[s] = mfma16(ah, bf, a2[s]);
      }
    }
    __syncthreads();
    #pragma unroll
    for(int s=0;s<4;s++){
      float bias = bb[half*64 + s*16+ln];
      #pragma unroll
      for(int r=0;r<4;r++)
        out[(size_t)(n0+wid*16+quad*4+r)*128 + half*64 + s*16+ln] = a2[s][r] + bias;
    }
  }
}

// ---------------------------------------------------------------------------
extern "C" void kernel_launch(void* const* d_in, const int* in_sizes, int n_in,
                              void* d_out, int out_size, void* d_ws, size_t ws_size,
                              hipStream_t stream)
{
  (void)in_sizes; (void)n_in; (void)out_size; (void)ws_size;
  const float* x      = (const float*)d_in[0];
  const float* eattr  = (const float*)d_in[1];
  const int*   eidx   = (const int*)d_in[2];
  const int*   lidx   = (const int*)d_in[3];
  /* d_in[4] edge_batch: implied by fixed per-graph layout */
  const float* wmlp   = (const float*)d_in[5];
  const float* bmlp   = (const float*)d_in[6];
  const float* wu     = (const float*)d_in[7];
  const float* wvv    = (const float*)d_in[8];
  const float* wedge  = (const float*)d_in[9];
  const float* wrel   = (const float*)d_in[10];
  const float* brel   = (const float*)d_in[11];
  const float* wroot  = (const float*)d_in[12];
  const float* aatt   = (const float*)d_in[13];
  const float* abias  = (const float*)d_in[14];
  const float* wgout  = (const float*)d_in[15];
  const float* bgout  = (const float*)d_in[16];
  const float* wblock = (const float*)d_in[17];
  const float* bblock = (const float*)d_in[18];

  char* ws = (char*)d_ws;
  ushort* h  = (ushort*)(ws);                         // bf16 [N,128]   25.2 MB
  float*  hu = (float*)(ws + 25165824);               // fp32 [N,128]   50.3 MB
  float*  hv = (float*)(ws + 75497472);               // fp32 [N,128]   50.3 MB
  float*  zf = (float*)(ws + 125829120);              // fp32 [N,128]   50.3 MB

  k_feat <<<NN/64, 256, 0, stream>>>(x, wmlp, bmlp, wu, wvv, h, hu, hv);
  k_graph<<<NGR,   256, 0, stream>>>(hu, hv, h, eattr, eidx, lidx, wedge, wrel, brel,
                                     wroot, aatt, abias, wgout, bgout, zf);
  k_final<<<NN/64, 256, 0, stream>>>(zf, wblock, bblock, (float*)d_out);
}

// Round 5
// 876.563 us; speedup vs baseline: 1.0587x; 1.0587x over previous
//
#include <hip/hip_runtime.h>

#define NGR 4096
#define NPG 24
#define EPG 48
#define LPG 144
#define NITER 4
#define HID 128
#define NN (NGR*NPG)
#define NE (NGR*EPG)
#define NL (NGR*LPG)

typedef unsigned int uint;
typedef unsigned short ushort;
typedef short bf16x8 __attribute__((ext_vector_type(8)));
typedef float f32x4 __attribute__((ext_vector_type(4)));
typedef float f32x2 __attribute__((ext_vector_type(2)));

__device__ __forceinline__ float b2f(ushort u){ return __uint_as_float(((uint)u)<<16); }
__device__ __forceinline__ float b2f_lo(uint u){ return __uint_as_float(u<<16); }
__device__ __forceinline__ float b2f_hi(uint u){ return __uint_as_float(u & 0xFFFF0000u); }
__device__ __forceinline__ ushort f2b(float f){
  uint x = __float_as_uint(f);
  x += 0x7FFFu + ((x>>16)&1u);
  return (ushort)(x>>16);
}
__device__ __forceinline__ ushort f2b_lo(float v){
  ushort hi = f2b(v);
  return f2b(v - b2f(hi));
}
__device__ __forceinline__ float wredsum(float v){
  #pragma unroll
  for(int m=32;m;m>>=1) v += __shfl_xor(v, m, 64);
  return v;
}
__device__ __forceinline__ f32x4 mfma16(bf16x8 a, bf16x8 b, f32x4 c){
  return __builtin_amdgcn_mfma_f32_16x16x32_bf16(a, b, c, 0, 0, 0);
}

// ---------------------------------------------------------------------------
// K1: h = x@w_mlp + b (bf16x3 MFMA) ; hu = h@w_u ; hv = h@w_v (bf16x3)
// ---------------------------------------------------------------------------
__global__ __launch_bounds__(256) void k_feat(
    const float* __restrict__ x, const float* __restrict__ wmlp, const float* __restrict__ bmlp,
    const float* __restrict__ wu, const float* __restrict__ wvv,
    ushort* __restrict__ h, float* __restrict__ hu, float* __restrict__ hv)
{
  __shared__ __align__(16) ushort lds[26624];
  ushort* Ah = lds;            // stride 104
  ushort* Al = lds + 6656;
  ushort* Wt = lds + 13312;
  ushort* Ah2 = lds;           // stride 136
  ushort* Al2 = lds + 8704;
  ushort* Wt2 = lds + 17408;

  const int tid = threadIdx.x;
  const int lane = tid & 63, wid = tid >> 6;
  const int quad = lane >> 4, ln = lane & 15;
  const int n0 = blockIdx.x * 64;
  const int mrow = wid*16 + ln;
  const f32x4 z4 = {0.f,0.f,0.f,0.f};

  for(int idx=tid; idx<64*70; idx+=256){ int r=idx/70, cc=idx-r*70;
    float v = x[(size_t)(n0+r)*70+cc]; ushort hi=f2b(v);
    Ah[r*104+cc]=hi; Al[r*104+cc]=f2b(v-b2f(hi)); }
  for(int idx=tid; idx<64*34; idx+=256){ int r=idx/34, o=idx-r*34;
    Ah[r*104+70+o]=0; Al[r*104+70+o]=0; }
  for(int idx=tid; idx<70*128; idx+=256){ int k=idx>>7, n=idx&127; Wt[n*104+k]=f2b(wmlp[idx]); }
  for(int idx=tid; idx<128*34; idx+=256){ int n=idx/34, o=idx-n*34; Wt[n*104+70+o]=0; }
  __syncthreads();

  f32x4 acc[8];
  #pragma unroll
  for(int s=0;s<8;s++) acc[s]=z4;
  #pragma unroll
  for(int ks=0; ks<3; ks++){
    const int ko = ks*32 + quad*8;
    bf16x8 ah = *(const bf16x8*)&Ah[mrow*104 + ko];
    bf16x8 al = *(const bf16x8*)&Al[mrow*104 + ko];
    #pragma unroll
    for(int s=0;s<8;s++){
      bf16x8 bf = *(const bf16x8*)&Wt[(s*16+ln)*104 + ko];
      acc[s] = mfma16(ah, bf, acc[s]);
      acc[s] = mfma16(al, bf, acc[s]);
    }
  }
  __syncthreads();
  for(int idx=tid; idx<70*128; idx+=256){ int k=idx>>7, n=idx&127; Wt[n*104+k]=f2b_lo(wmlp[idx]); }
  __syncthreads();
  #pragma unroll
  for(int ks=0; ks<3; ks++){
    const int ko = ks*32 + quad*8;
    bf16x8 ah = *(const bf16x8*)&Ah[mrow*104 + ko];
    #pragma unroll
    for(int s=0;s<8;s++){
      bf16x8 bf = *(const bf16x8*)&Wt[(s*16+ln)*104 + ko];
      acc[s] = mfma16(ah, bf, acc[s]);
    }
  }
  __syncthreads();

  #pragma unroll
  for(int s=0;s<8;s++){
    float bb = bmlp[s*16+ln];
    #pragma unroll
    for(int r=0;r<4;r++){
      float hval = acc[s][r] + bb;
      int row = wid*16+quad*4+r, col = s*16+ln;
      ushort hi = f2b(hval);
      h[(size_t)(n0+row)*128 + col] = hi;
      Ah2[row*136+col] = hi;
      Al2[row*136+col] = f2b(hval - b2f(hi));
    }
  }
  __syncthreads();

  for(int w=0; w<2; w++){
    const float* wsp = w ? wvv : wu;
    float* dst = w ? hv : hu;
    for(int half=0; half<2; half++){
      for(int idx=tid; idx<64*128; idx+=256){ int n=idx>>7, k=idx&127;
        Wt2[n*136+k]=f2b(wsp[k*128 + half*64 + n]); }
      __syncthreads();
      f32x4 a2[4];
      #pragma unroll
      for(int s=0;s<4;s++) a2[s]=z4;
      #pragma unroll
      for(int ks=0;ks<4;ks++){
        const int ko = ks*32 + quad*8;
        bf16x8 ah = *(const bf16x8*)&Ah2[mrow*136 + ko];
        bf16x8 al = *(const bf16x8*)&Al2[mrow*136 + ko];
        #pragma unroll
        for(int s=0;s<4;s++){
          bf16x8 bf = *(const bf16x8*)&Wt2[(s*16+ln)*136 + ko];
          a2[s] = mfma16(ah, bf, a2[s]);
          a2[s] = mfma16(al, bf, a2[s]);
        }
      }
      __syncthreads();
      for(int idx=tid; idx<64*128; idx+=256){ int n=idx>>7, k=idx&127;
        Wt2[n*136+k]=f2b_lo(wsp[k*128 + half*64 + n]); }
      __syncthreads();
      #pragma unroll
      for(int ks=0;ks<4;ks++){
        const int ko = ks*32 + quad*8;
        bf16x8 ah = *(const bf16x8*)&Ah2[mrow*136 + ko];
        #pragma unroll
        for(int s=0;s<4;s++){
          bf16x8 bf = *(const bf16x8*)&Wt2[(s*16+ln)*136 + ko];
          a2[s] = mfma16(ah, bf, a2[s]);
        }
      }
      __syncthreads();
      #pragma unroll
      for(int s=0;s<4;s++)
        #pragma unroll
        for(int r=0;r<4;r++)
          dst[(size_t)(n0+wid*16+quad*4+r)*128 + half*64 + s*16+ln] = a2[s][r];
    }
  }
}

// ---------------------------------------------------------------------------
// K2: one workgroup per graph. Waves 1-3: feature recursion (16 edges each);
// wave 0: scalar P/R recursion + softmax (linearity of dot products).
// ---------------------------------------------------------------------------
__global__ __launch_bounds__(256) void k_graph(
  const float* __restrict__ hu, const float* __restrict__ hv,
  const ushort* __restrict__ h, const float* __restrict__ ea,
  const int* __restrict__ eidx, const int* __restrict__ lidx,
  const float* __restrict__ wedge, const float* __restrict__ wrel, const float* __restrict__ brel,
  const float* __restrict__ wroot, const float* __restrict__ aatt, const float* __restrict__ abias,
  const float* __restrict__ wgout, const float* __restrict__ bgout,
  float* __restrict__ z)
{
  const int g = blockIdx.x;
  const int tid = threadIdx.x;
  const int lane = tid & 63, wid = tid >> 6;
  const int c = lane;
  const int E0 = g*EPG, L0 = g*LPG;

  __shared__ __align__(16) float buf0[EPG*HID];   // 24576 B
  __shared__ __align__(16) float buf1[EPG*HID];   // 24576 B
  __shared__ float gsf[NITER][HID];               // 2048 B (also aliased as cnt2 in setup)
  __shared__ float xc[EPG];
  __shared__ float Ps[EPG], Rs[EPG];
  __shared__ ushort csr_src[LPG];
  __shared__ ushort rstart[EPG+1];
  __shared__ uint cnt[EPG];
  __shared__ ushort dstl[EPG];
  __shared__ float score[NITER], wts[NITER];
  uint* cnt2 = (uint*)&gsf[0][0];

  // ---- setup: CSR build ----
  if(tid < EPG){ cnt[tid]=0u; cnt2[tid]=0u; dstl[tid] = (ushort)(eidx[NE + E0 + tid] - g*NPG); }
  __syncthreads();
  int myld=0, myls=0;
  if(tid < LPG){ myls = lidx[L0+tid] - E0; myld = lidx[NL + L0 + tid] - E0;
                 atomicAdd(&cnt[myld], 1u); }
  __syncthreads();
  if(wid==0){
    uint v = (lane<EPG) ? cnt[lane] : 0u;
    #pragma unroll
    for(int d=1; d<64; d<<=1){ uint n=__shfl_up(v,d,64); if(lane>=d) v+=n; }
    if(lane==0) rstart[0]=0;
    if(lane<EPG) rstart[lane+1]=(ushort)v;
  }
  __syncthreads();
  if(tid < LPG){ uint slot = (uint)rstart[myld] + atomicAdd(&cnt2[myld],1u); csr_src[slot]=(ushort)myls; }

  // ---- e0 (waves 1-3, 16 edges each); P/R e0-dots via wredsum ----
  const float brel_f = brel[0];
  f32x2 e0r[16];
  if(wid > 0){
    const float wr0 = wrel[2*c],  wr1 = wrel[2*c+1];
    const float wo0 = wroot[2*c], wo1 = wroot[2*c+1];
    float we0[6], we1[6];
    #pragma unroll
    for(int k=0;k<6;k++){ we0[k]=wedge[k*128 + 2*c]; we1[k]=wedge[k*128 + 2*c+1]; }
    #pragma unroll
    for(int ii=0; ii<16; ii++){
      int i = (wid-1)*16+ii, e = E0+i;
      int sg = eidx[e], dg = eidx[NE + e];
      f32x2 du = ((const f32x2*)hu)[sg*64 + c];
      f32x2 dv = ((const f32x2*)hv)[dg*64 + c];
      float a0 = du.x + dv.x, a1 = du.y + dv.y;
      #pragma unroll
      for(int k=0;k<6;k++){ float ev = ea[e*6+k]; a0 += ev*we0[k]; a1 += ev*we1[k]; }
      a0 *= (1.f/3.f); a1 *= (1.f/3.f);
      e0r[ii].x = a0; e0r[ii].y = a1;
      ((f32x2*)buf0)[i*64 + c] = e0r[ii];
      float pv = wredsum(a0*wr0 + a1*wr1);
      float rv = wredsum(a0*wo0 + a1*wo1);
      if(lane==0){ Ps[i]=pv; Rs[i]=rv; }
    }
  }
  // zero gsf (after cnt2 alias is dead)
  __syncthreads();
  for(int idx=tid; idx<NITER*HID; idx+=256) ((float*)gsf)[idx]=0.f;
  __syncthreads();

  // wave0 scalar-loop registers
  float pe=0.f, re=0.f; int js0=0, je0=0;
  if(wid==0){
    if(lane<EPG){ pe=Ps[lane]; re=Rs[lane]; js0=rstart[lane]; je0=rstart[lane+1]; }
  }

  // ---- Pass A: 4 iterations ----
  for(int t=0; t<NITER; t++){
    const f32x2* prev = (t&1) ? (const f32x2*)buf1 : (const f32x2*)buf0;
    f32x2* cur       = (t&1) ? (f32x2*)buf0       : (f32x2*)buf1;
    if(wid > 0){
      #pragma unroll
      for(int ii=0; ii<16; ii++){
        int i = (wid-1)*16+ii;
        float a0 = e0r[ii].x, a1 = e0r[ii].y;
        int js = rstart[i], je = rstart[i+1];
        for(int j=js;j<je;j++){
          f32x2 d = prev[(int)csr_src[j]*64 + c];
          a0 += d.x; a1 += d.y;
        }
        f32x2 o; o.x=a0; o.y=a1;
        cur[i*64+c] = o;
      }
    } else {
      // scalar P/R recursion + xc + softmax (wave-synchronous)
      float p = pe, r = re;
      for(int j=js0;j<je0;j++){ int s=csr_src[j]; p += Ps[s]; r += Rs[s]; }
      if(lane<EPG){ Ps[lane]=p; Rs[lane]=r; }
      float xv = r + brel_f;
      for(int j=js0;j<je0;j++) xv += Ps[csr_src[j]];
      float v = (lane<EPG) ? xv : -3.0e38f;
      float m = v;
      #pragma unroll
      for(int msk=32;msk;msk>>=1) m = fmaxf(m, __shfl_xor(m,msk,64));
      float e2 = (lane<EPG) ? __expf(v-m) : 0.f;
      float ssum = e2;
      #pragma unroll
      for(int msk=32;msk;msk>>=1) ssum += __shfl_xor(ssum,msk,64);
      if(lane<EPG) xc[lane] = e2/ssum;
    }
    __syncthreads();
    if(wid > 0){
      float gp0=0.f, gp1=0.f;
      #pragma unroll
      for(int ii=0; ii<16; ii++){
        int i = (wid-1)*16+ii;
        float sc = xc[i];
        f32x2 d = cur[i*64+c];
        gp0 += d.x*sc; gp1 += d.y*sc;
      }
      atomicAdd(&gsf[t][2*c],   gp0);
      atomicAdd(&gsf[t][2*c+1], gp1);
    }
    __syncthreads();
  }

  // ---- temporal attention: wave t computes score[t] ----
  {
    const int t = wid;
    float s0 = bgout[2*c], s1 = bgout[2*c+1];
    for(int k=0;k<128;k++){
      float gk = gsf[t][k];
      f32x2 w = ((const f32x2*)wgout)[k*64 + c];
      s0 += gk*w.x; s1 += gk*w.y;
    }
    float v = tanhf(s0)*aatt[(2*c)*4 + t] + tanhf(s1)*aatt[(2*c+1)*4 + t];
    v = wredsum(v);
    if(lane==0) score[t] = v + abias[t];
  }
  __syncthreads();
  if(tid==0){
    float m = fmaxf(fmaxf(score[0],score[1]), fmaxf(score[2],score[3]));
    float e0=__expf(score[0]-m), e1=__expf(score[1]-m), e2=__expf(score[2]-m), e3=__expf(score[3]-m);
    float s = e0+e1+e2+e3;
    wts[0]=e0/s; wts[1]=e1/s; wts[2]=e2/s; wts[3]=e3/s;
  }
  __syncthreads();

  // ---- Pass B: wacc from out4(buf0)/out3(buf1) snapshots; replay t=1,2 ----
  f32x2 wacc[16];
  const float w1=wts[0], w2=wts[1], w3=wts[2], w4=wts[3];
  if(wid > 0){
    #pragma unroll
    for(int ii=0; ii<16; ii++){
      int i = (wid-1)*16+ii;
      f32x2 a4 = ((const f32x2*)buf0)[i*64+c];
      f32x2 a3 = ((const f32x2*)buf1)[i*64+c];
      wacc[ii].x = w4*a4.x + w3*a3.x;
      wacc[ii].y = w4*a4.y + w3*a3.y;
      ((f32x2*)buf0)[i*64+c] = e0r[ii];   // own slot: read-then-write, safe
    }
  }
  __syncthreads();
  if(wid > 0){
    // replay out_1 (write to buf1)
    #pragma unroll
    for(int ii=0; ii<16; ii++){
      int i = (wid-1)*16+ii;
      float a0 = e0r[ii].x, a1 = e0r[ii].y;
      int js = rstart[i], je = rstart[i+1];
      for(int j=js;j<je;j++){
        f32x2 d = ((const f32x2*)buf0)[(int)csr_src[j]*64 + c];
        a0 += d.x; a1 += d.y;
      }
      f32x2 o; o.x=a0; o.y=a1;
      ((f32x2*)buf1)[i*64+c] = o;
      wacc[ii].x += w1*a0; wacc[ii].y += w1*a1;
    }
  }
  __syncthreads();
  if(wid > 0){
    // replay out_2 (no write needed)
    #pragma unroll
    for(int ii=0; ii<16; ii++){
      int i = (wid-1)*16+ii;
      float a0 = e0r[ii].x, a1 = e0r[ii].y;
      int js = rstart[i], je = rstart[i+1];
      for(int j=js;j<je;j++){
        f32x2 d = ((const f32x2*)buf1)[(int)csr_src[j]*64 + c];
        a0 += d.x; a1 += d.y;
      }
      wacc[ii].x += w2*a0; wacc[ii].y += w2*a1;
    }
  }
  __syncthreads();

  // ---- scatter to dst nodes; z = h + nacc ----
  float* nacc = buf0;   // 24*128 floats
  for(int idx=tid; idx<NPG*HID; idx+=256) nacc[idx]=0.f;
  __syncthreads();
  if(wid > 0){
    #pragma unroll
    for(int ii=0; ii<16; ii++){
      int i = (wid-1)*16+ii;
      int dn = dstl[i];
      atomicAdd(&nacc[dn*128 + 2*c],   wacc[ii].x);
      atomicAdd(&nacc[dn*128 + 2*c+1], wacc[ii].y);
    }
  }
  __syncthreads();
  for(int idx=tid; idx<NPG*64; idx+=256){
    int n = idx>>6, cc = idx&63;
    uint hh = ((const uint*)h)[(g*NPG+n)*64 + cc];
    f32x2 zo;
    zo.x = b2f_lo(hh) + nacc[n*128 + 2*cc];
    zo.y = b2f_hi(hh) + nacc[n*128 + 2*cc+1];
    ((f32x2*)z)[(g*NPG+n)*64 + cc] = zo;
  }
}

// ---------------------------------------------------------------------------
// K3: out = z @ w_block + b_block  (bf16x3 MFMA, fp32 in/out)
// ---------------------------------------------------------------------------
__global__ __launch_bounds__(256) void k_final(
    const float* __restrict__ zf, const float* __restrict__ wb, const float* __restrict__ bb,
    float* __restrict__ out)
{
  __shared__ __align__(16) ushort lds[26112];
  ushort* Ah = lds;
  ushort* Al = lds + 8704;
  ushort* Wt = lds + 17408;
  const int tid = threadIdx.x;
  const int lane = tid & 63, wid = tid >> 6;
  const int quad = lane >> 4, ln = lane & 15;
  const int n0 = blockIdx.x * 64;
  const int mrow = wid*16 + ln;
  const f32x4 z4 = {0.f,0.f,0.f,0.f};

  for(int idx=tid; idx<64*128; idx+=256){ int r=idx>>7, k=idx&127;
    float v = zf[(size_t)(n0+r)*128+k]; ushort hi=f2b(v);
    Ah[r*136+k]=hi; Al[r*136+k]=f2b(v-b2f(hi)); }
  __syncthreads();

  for(int half=0; half<2; half++){
    for(int idx=tid; idx<64*128; idx+=256){ int n=idx>>7, k=idx&127;
      Wt[n*136+k]=f2b(wb[k*128 + half*64 + n]); }
    __syncthreads();
    f32x4 a2[4];
    #pragma unroll
    for(int s=0;s<4;s++) a2[s]=z4;
    #pragma unroll
    for(int ks=0;ks<4;ks++){
      const int ko = ks*32 + quad*8;
      bf16x8 ah = *(const bf16x8*)&Ah[mrow*136 + ko];
      bf16x8 al = *(const bf16x8*)&Al[mrow*136 + ko];
      #pragma unroll
      for(int s=0;s<4;s++){
        bf16x8 bf = *(const bf16x8*)&Wt[(s*16+ln)*136 + ko];
        a2[s] = mfma16(ah, bf, a2[s]);
        a2[s] = mfma16(al, bf, a2[s]);
      }
    }
    __syncthreads();
    for(int idx=tid; idx<64*128; idx+=256){ int n=idx>>7, k=idx&127;
      Wt[n*136+k]=f2b_lo(wb[k*128 + half*64 + n]); }
    __syncthreads();
    #pragma unroll
    for(int ks=0;ks<4;ks++){
      const int ko = ks*32 + quad*8;
      bf16x8 ah = *(const bf16x8*)&Ah[mrow*136 + ko];
      #pragma unroll
      for(int s=0;s<4;s++){
        bf16x8 bf = *(const bf16x8*)&Wt[(s*16+ln)*136 + ko];
        a2[s] = mfma16(ah, bf, a2[s]);
      }
    }
    __syncthreads();
    #pragma unroll
    for(int s=0;s<4;s++){
      float bias = bb[half*64 + s*16+ln];
      #pragma unroll
      for(int r=0;r<4;r++)
        out[(size_t)(n0+wid*16+quad*4+r)*128 + half*64 + s*16+ln] = a2[s][r] + bias;
    }
  }
}

// ---------------------------------------------------------------------------
extern "C" void kernel_launch(void* const* d_in, const int* in_sizes, int n_in,
                              void* d_out, int out_size, void* d_ws, size_t ws_size,
                              hipStream_t stream)
{
  (void)in_sizes; (void)n_in; (void)out_size; (void)ws_size;
  const float* x      = (const float*)d_in[0];
  const float* eattr  = (const float*)d_in[1];
  const int*   eidx   = (const int*)d_in[2];
  const int*   lidx   = (const int*)d_in[3];
  const float* wmlp   = (const float*)d_in[5];
  const float* bmlp   = (const float*)d_in[6];
  const float* wu     = (const float*)d_in[7];
  const float* wvv    = (const float*)d_in[8];
  const float* wedge  = (const float*)d_in[9];
  const float* wrel   = (const float*)d_in[10];
  const float* brel   = (const float*)d_in[11];
  const float* wroot  = (const float*)d_in[12];
  const float* aatt   = (const float*)d_in[13];
  const float* abias  = (const float*)d_in[14];
  const float* wgout  = (const float*)d_in[15];
  const float* bgout  = (const float*)d_in[16];
  const float* wblock = (const float*)d_in[17];
  const float* bblock = (const float*)d_in[18];

  char* ws = (char*)d_ws;
  ushort* h  = (ushort*)(ws);                         // bf16 [N,128]
  float*  hu = (float*)(ws + 25165824);               // fp32 [N,128]
  float*  hv = (float*)(ws + 75497472);               // fp32 [N,128]
  float*  zf = (float*)(ws + 125829120);              // fp32 [N,128]

  k_feat <<<NN/64, 256, 0, stream>>>(x, wmlp, bmlp, wu, wvv, h, hu, hv);
  k_graph<<<NGR,   256, 0, stream>>>(hu, hv, h, eattr, eidx, lidx, wedge, wrel, brel,
                                     wroot, aatt, abias, wgout, bgout, zf);
  k_final<<<NN/64, 256, 0, stream>>>(zf, wblock, bblock, (float*)d_out);
}

// Round 6
// 746.981 us; speedup vs baseline: 1.2424x; 1.1735x over previous
//
#include <hip/hip_runtime.h>

#define NGR 4096
#define NPG 24
#define EPG 48
#define LPG 144
#define NITER 4
#define HID 128
#define NN (NGR*NPG)
#define NE (NGR*EPG)
#define NL (NGR*LPG)

typedef unsigned int uint;
typedef unsigned short ushort;
typedef short bf16x8 __attribute__((ext_vector_type(8)));
typedef unsigned short u16x4 __attribute__((ext_vector_type(4)));
typedef float f32x4 __attribute__((ext_vector_type(4)));
typedef float f32x2 __attribute__((ext_vector_type(2)));

__device__ __forceinline__ float b2f(ushort u){ return __uint_as_float(((uint)u)<<16); }
__device__ __forceinline__ float b2f_lo(uint u){ return __uint_as_float(u<<16); }
__device__ __forceinline__ float b2f_hi(uint u){ return __uint_as_float(u & 0xFFFF0000u); }
__device__ __forceinline__ ushort f2b(float f){
  uint x = __float_as_uint(f);
  x += 0x7FFFu + ((x>>16)&1u);
  return (ushort)(x>>16);
}
__device__ __forceinline__ ushort f2b_lo(float v){
  ushort hi = f2b(v);
  return f2b(v - b2f(hi));
}
__device__ __forceinline__ float wredsum(float v){
  #pragma unroll
  for(int m=32;m;m>>=1) v += __shfl_xor(v, m, 64);
  return v;
}
__device__ __forceinline__ f32x4 mfma16(bf16x8 a, bf16x8 b, f32x4 c){
  return __builtin_amdgcn_mfma_f32_16x16x32_bf16(a, b, c, 0, 0, 0);
}

// ---------------------------------------------------------------------------
// K1: h = x@w_mlp + b (bf16x3 MFMA) ; hu = h@w_u ; hv = h@w_v (bf16x3)
// ---------------------------------------------------------------------------
__global__ __launch_bounds__(256) void k_feat(
    const float* __restrict__ x, const float* __restrict__ wmlp, const float* __restrict__ bmlp,
    const float* __restrict__ wu, const float* __restrict__ wvv,
    ushort* __restrict__ h, float* __restrict__ hu, float* __restrict__ hv)
{
  __shared__ __align__(16) ushort lds[26624];
  ushort* Ah = lds;            // stride 104
  ushort* Al = lds + 6656;
  ushort* Wt = lds + 13312;
  ushort* Ah2 = lds;           // stride 136
  ushort* Al2 = lds + 8704;
  ushort* Wt2 = lds + 17408;

  const int tid = threadIdx.x;
  const int lane = tid & 63, wid = tid >> 6;
  const int quad = lane >> 4, ln = lane & 15;
  const int n0 = blockIdx.x * 64;
  const int mrow = wid*16 + ln;
  const f32x4 z4 = {0.f,0.f,0.f,0.f};

  for(int idx=tid; idx<64*70; idx+=256){ int r=idx/70, cc=idx-r*70;
    float v = x[(size_t)(n0+r)*70+cc]; ushort hi=f2b(v);
    Ah[r*104+cc]=hi; Al[r*104+cc]=f2b(v-b2f(hi)); }
  for(int idx=tid; idx<64*34; idx+=256){ int r=idx/34, o=idx-r*34;
    Ah[r*104+70+o]=0; Al[r*104+70+o]=0; }
  for(int idx=tid; idx<70*128; idx+=256){ int k=idx>>7, n=idx&127; Wt[n*104+k]=f2b(wmlp[idx]); }
  for(int idx=tid; idx<128*34; idx+=256){ int n=idx/34, o=idx-n*34; Wt[n*104+70+o]=0; }
  __syncthreads();

  f32x4 acc[8];
  #pragma unroll
  for(int s=0;s<8;s++) acc[s]=z4;
  #pragma unroll
  for(int ks=0; ks<3; ks++){
    const int ko = ks*32 + quad*8;
    bf16x8 ah = *(const bf16x8*)&Ah[mrow*104 + ko];
    bf16x8 al = *(const bf16x8*)&Al[mrow*104 + ko];
    #pragma unroll
    for(int s=0;s<8;s++){
      bf16x8 bf = *(const bf16x8*)&Wt[(s*16+ln)*104 + ko];
      acc[s] = mfma16(ah, bf, acc[s]);
      acc[s] = mfma16(al, bf, acc[s]);
    }
  }
  __syncthreads();
  for(int idx=tid; idx<70*128; idx+=256){ int k=idx>>7, n=idx&127; Wt[n*104+k]=f2b_lo(wmlp[idx]); }
  __syncthreads();
  #pragma unroll
  for(int ks=0; ks<3; ks++){
    const int ko = ks*32 + quad*8;
    bf16x8 ah = *(const bf16x8*)&Ah[mrow*104 + ko];
    #pragma unroll
    for(int s=0;s<8;s++){
      bf16x8 bf = *(const bf16x8*)&Wt[(s*16+ln)*104 + ko];
      acc[s] = mfma16(ah, bf, acc[s]);
    }
  }
  __syncthreads();

  #pragma unroll
  for(int s=0;s<8;s++){
    float bb = bmlp[s*16+ln];
    #pragma unroll
    for(int r=0;r<4;r++){
      float hval = acc[s][r] + bb;
      int row = wid*16+quad*4+r, col = s*16+ln;
      ushort hi = f2b(hval);
      h[(size_t)(n0+row)*128 + col] = hi;
      Ah2[row*136+col] = hi;
      Al2[row*136+col] = f2b(hval - b2f(hi));
    }
  }
  __syncthreads();

  for(int w=0; w<2; w++){
    const float* wsp = w ? wvv : wu;
    float* dst = w ? hv : hu;
    for(int half=0; half<2; half++){
      for(int idx=tid; idx<64*128; idx+=256){ int n=idx>>7, k=idx&127;
        Wt2[n*136+k]=f2b(wsp[k*128 + half*64 + n]); }
      __syncthreads();
      f32x4 a2[4];
      #pragma unroll
      for(int s=0;s<4;s++) a2[s]=z4;
      #pragma unroll
      for(int ks=0;ks<4;ks++){
        const int ko = ks*32 + quad*8;
        bf16x8 ah = *(const bf16x8*)&Ah2[mrow*136 + ko];
        bf16x8 al = *(const bf16x8*)&Al2[mrow*136 + ko];
        #pragma unroll
        for(int s=0;s<4;s++){
          bf16x8 bf = *(const bf16x8*)&Wt2[(s*16+ln)*136 + ko];
          a2[s] = mfma16(ah, bf, a2[s]);
          a2[s] = mfma16(al, bf, a2[s]);
        }
      }
      __syncthreads();
      for(int idx=tid; idx<64*128; idx+=256){ int n=idx>>7, k=idx&127;
        Wt2[n*136+k]=f2b_lo(wsp[k*128 + half*64 + n]); }
      __syncthreads();
      #pragma unroll
      for(int ks=0;ks<4;ks++){
        const int ko = ks*32 + quad*8;
        bf16x8 ah = *(const bf16x8*)&Ah2[mrow*136 + ko];
        #pragma unroll
        for(int s=0;s<4;s++){
          bf16x8 bf = *(const bf16x8*)&Wt2[(s*16+ln)*136 + ko];
          a2[s] = mfma16(ah, bf, a2[s]);
        }
      }
      __syncthreads();
      #pragma unroll
      for(int s=0;s<4;s++)
        #pragma unroll
        for(int r=0;r<4;r++)
          dst[(size_t)(n0+wid*16+quad*4+r)*128 + half*64 + s*16+ln] = a2[s][r];
    }
  }
}

// ---------------------------------------------------------------------------
// K2: one workgroup per graph. Dense 48x48 adjacency MFMA recursion.
//   out stored in LDS transposed [n][k] as bf16 hi+lo (fp32-accurate split).
//   e0 rides as MFMA C operand (registers). xc softmaxes precomputed via
//   scalar linear recursion (P_t = Pe + A P_{t-1}; aggr.wrel = P_{t+1}-Pe).
// ---------------------------------------------------------------------------
__global__ __launch_bounds__(256) void k_graph(
  const float* __restrict__ hu, const float* __restrict__ hv,
  const ushort* __restrict__ h, const float* __restrict__ ea,
  const int* __restrict__ eidx, const int* __restrict__ lidx,
  const float* __restrict__ wedge, const float* __restrict__ wrel, const float* __restrict__ brel,
  const float* __restrict__ wroot, const float* __restrict__ aatt, const float* __restrict__ abias,
  const float* __restrict__ wgout, const float* __restrict__ bgout,
  float* __restrict__ z)
{
  const int g = blockIdx.x;
  const int tid = threadIdx.x;
  const int lane = tid & 63, wid = tid >> 6;
  const int q = lane >> 4, ln = lane & 15;
  const int E0 = g*EPG, L0 = g*LPG;

  __shared__ __align__(16) ushort OUT_hi[128*72];   // 18432 B, [n][k] stride 72
  __shared__ __align__(16) ushort OUT_lo[128*72];   // 18432 B
  __shared__ __align__(16) ushort A_bf[48*72];      // 6912 B, [dst][src] stride 72
  __shared__ float eaL[288];
  __shared__ int esrc[48], edst[48];
  __shared__ ushort dstl[48];
  __shared__ float Pe[48], Re[48];
  __shared__ float xcs[NITER][48];
  __shared__ float gsf[NITER][HID];
  __shared__ float score[NITER], wts[NITER];
  uint*  A_u  = (uint*)OUT_hi;    // [48][64] alias (pre-loop only)
  float* nacc = (float*)OUT_hi;   // [24][128] alias (post-loop only)

  // ---- setup ----
  for(int idx=tid; idx<48*64; idx+=256) A_u[idx]=0u;
  if(tid<48){
    int s=eidx[E0+tid], d=eidx[NE+E0+tid];
    esrc[tid]=s; edst[tid]=d; dstl[tid]=(ushort)(d - g*NPG);
    Pe[tid]=0.f; Re[tid]=0.f;
  }
  for(int idx=tid; idx<288; idx+=256) eaL[idx]=ea[(size_t)E0*6+idx];
  __syncthreads();
  if(tid<LPG){
    int ls=lidx[L0+tid]-E0, ld=lidx[NL+L0+tid]-E0;
    atomicAdd(&A_u[ld*64+ls],1u);
  }
  __syncthreads();
  for(int idx=tid; idx<48*64; idx+=256){ int i=idx>>6, j=idx&63;
    A_bf[i*72+j]=f2b((float)A_u[idx]); }   // small ints: exact in bf16

  // per-lane params: this wave owns features nA, nA+16 (2 N-tiles)
  const int nA = wid*32 + ln;
  const int nB2 = nA + 16;
  const float wrel0=wrel[nA],  wrel1=wrel[nB2];
  const float wroot0=wroot[nA], wroot1=wroot[nB2];
  float wed[2][6];
  #pragma unroll
  for(int k=0;k<6;k++){ wed[0][k]=wedge[k*128+nA]; wed[1][k]=wedge[k*128+nB2]; }
  const float brel_f=brel[0];

  // ---- e0 fragments (C-layout: rows m=mt*16+q*4+r, cols nA/nB2) ----
  f32x4 e0f[3][2];
  #pragma unroll
  for(int mt=0;mt<3;mt++)
    #pragma unroll
    for(int r=0;r<4;r++){
      int m = mt*16+q*4+r;
      int sg=esrc[m], dg=edst[m];
      float v0 = hu[(size_t)sg*128+nA]  + hv[(size_t)dg*128+nA];
      float v1 = hu[(size_t)sg*128+nB2] + hv[(size_t)dg*128+nB2];
      #pragma unroll
      for(int k=0;k<6;k++){ float e=eaL[m*6+k]; v0+=e*wed[0][k]; v1+=e*wed[1][k]; }
      e0f[mt][0][r]=v0*(1.f/3.f);
      e0f[mt][1][r]=v1*(1.f/3.f);
    }

  // ---- Pe/Re = e0 . wrel / wroot (frag reduce + LDS atomics) ----
  #pragma unroll
  for(int mt=0;mt<3;mt++){
    #pragma unroll
    for(int r=0;r<4;r++){
      float pp = e0f[mt][0][r]*wrel0  + e0f[mt][1][r]*wrel1;
      float rr = e0f[mt][0][r]*wroot0 + e0f[mt][1][r]*wroot1;
      #pragma unroll
      for(int msk=1;msk<16;msk<<=1){ pp+=__shfl_xor(pp,msk,64); rr+=__shfl_xor(rr,msk,64); }
      if(ln==0){ atomicAdd(&Pe[mt*16+q*4+r],pp); atomicAdd(&Re[mt*16+q*4+r],rr); }
    }
  }
  __syncthreads();   // A_bf + Pe/Re complete; A_u dead

  // ---- A-frags (resident); write out_0 = e0; zero K-padding ----
  bf16x8 Af[3][2];
  #pragma unroll
  for(int mt=0;mt<3;mt++){
    Af[mt][0]=*(const bf16x8*)&A_bf[(mt*16+ln)*72 + q*8];
    Af[mt][1]=*(const bf16x8*)&A_bf[(mt*16+ln)*72 + q*8 + 32];
  }
  #pragma unroll
  for(int mt=0;mt<3;mt++)
    #pragma unroll
    for(int nt=0;nt<2;nt++){
      u16x4 hh, llv;
      #pragma unroll
      for(int r=0;r<4;r++){ float v=e0f[mt][nt][r]; ushort hb=f2b(v);
        hh[r]=hb; llv[r]=f2b(v-b2f(hb)); }
      int ncol = nA + nt*16;
      *(u16x4*)&OUT_hi[ncol*72 + mt*16 + q*4] = hh;
      *(u16x4*)&OUT_lo[ncol*72 + mt*16 + q*4] = llv;
    }
  for(int idx=tid; idx<128*16; idx+=256){ int n=idx>>4, kk=48+(idx&15);
    OUT_hi[n*72+kk]=0; OUT_lo[n*72+kk]=0; }
  __syncthreads();

  // ---- wave0: scalar P/R recursion -> xcs[t] (shuffle-broadcast, no LDS hazard) ----
  if(wid==0){
    const int arow = (lane<48)? lane : 0;
    float pprev=(lane<48)?Pe[lane]:0.f;
    float rprev=(lane<48)?Re[lane]:0.f;
    const float pe_l=pprev, re_l=rprev;
    float rlast=rprev;
    #pragma unroll
    for(int t=1;t<=5;t++){
      float s=0.f, sr=0.f;
      for(int j=0;j<48;j++){
        float a = b2f(A_bf[arow*72+j]);
        float pj=__shfl(pprev,j,64);
        float rj=__shfl(rprev,j,64);
        s+=a*pj; sr+=a*rj;
      }
      s+=pe_l; sr+=re_l;
      if(t>=2){
        // xc_{t-1} = P_t - Pe + R_{t-1} + brel ; softmax over 48 edges
        float xv = s - pe_l + rlast + brel_f;
        float v=(lane<48)?xv:-3.0e38f;
        float mx=v;
        #pragma unroll
        for(int msk=32;msk;msk>>=1) mx=fmaxf(mx,__shfl_xor(mx,msk,64));
        float e2=(lane<48)?__expf(v-mx):0.f;
        float ss=e2;
        #pragma unroll
        for(int msk=32;msk;msk>>=1) ss+=__shfl_xor(ss,msk,64);
        if(lane<48) xcs[t-2][lane]=e2/ss;
      }
      pprev=s; rprev=sr; rlast=sr;
    }
  }
  __syncthreads();

  // ---- MFMA recursion: out_t = e0 + A @ out_{t-1} ----
  f32x4 Ocur[3][2];
  f32x4 hist[3][3][2];
  #pragma unroll
  for(int t=0;t<NITER;t++){
    bf16x8 Bh[2][2], Bl[2][2];
    #pragma unroll
    for(int nt=0;nt<2;nt++){
      int ncol = nA + nt*16;
      #pragma unroll
      for(int kc=0;kc<2;kc++){
        Bh[nt][kc]=*(const bf16x8*)&OUT_hi[ncol*72 + q*8 + kc*32];
        Bl[nt][kc]=*(const bf16x8*)&OUT_lo[ncol*72 + q*8 + kc*32];
      }
    }
    __syncthreads();   // all loads done before in-place overwrite
    #pragma unroll
    for(int mt=0;mt<3;mt++)
      #pragma unroll
      for(int nt=0;nt<2;nt++){
        f32x4 acc = e0f[mt][nt];
        acc = mfma16(Af[mt][0], Bh[nt][0], acc);
        acc = mfma16(Af[mt][1], Bh[nt][1], acc);
        acc = mfma16(Af[mt][0], Bl[nt][0], acc);
        acc = mfma16(Af[mt][1], Bl[nt][1], acc);
        Ocur[mt][nt]=acc;
      }
    float gp0=0.f, gp1=0.f;
    #pragma unroll
    for(int mt=0;mt<3;mt++)
      #pragma unroll
      for(int nt=0;nt<2;nt++){
        u16x4 hh, llv;
        #pragma unroll
        for(int r=0;r<4;r++){ float v=Ocur[mt][nt][r]; ushort hb=f2b(v);
          hh[r]=hb; llv[r]=f2b(v-b2f(hb)); }
        int ncol = nA + nt*16;
        *(u16x4*)&OUT_hi[ncol*72 + mt*16 + q*4] = hh;
        *(u16x4*)&OUT_lo[ncol*72 + mt*16 + q*4] = llv;
      }
    #pragma unroll
    for(int mt=0;mt<3;mt++)
      #pragma unroll
      for(int r=0;r<4;r++){
        float xcv = xcs[t][mt*16+q*4+r];
        gp0 += xcv*Ocur[mt][0][r];
        gp1 += xcv*Ocur[mt][1][r];
      }
    gp0 += __shfl_xor(gp0,16,64); gp0 += __shfl_xor(gp0,32,64);
    gp1 += __shfl_xor(gp1,16,64); gp1 += __shfl_xor(gp1,32,64);
    if(q==0){ gsf[t][nA]=gp0; gsf[t][nA+16]=gp1; }
    if(t<3){
      #pragma unroll
      for(int mt=0;mt<3;mt++)
        #pragma unroll
        for(int nt=0;nt<2;nt++) hist[t][mt][nt]=Ocur[mt][nt];
    }
    __syncthreads();
  }

  // ---- temporal attention: wave t computes score[t] ----
  {
    const int t = wid;
    const int c = lane;
    float s0 = bgout[2*c], s1 = bgout[2*c+1];
    for(int k=0;k<128;k++){
      float gk = gsf[t][k];
      f32x2 w = ((const f32x2*)wgout)[k*64 + c];
      s0 += gk*w.x; s1 += gk*w.y;
    }
    float v = tanhf(s0)*aatt[(2*c)*4 + t] + tanhf(s1)*aatt[(2*c+1)*4 + t];
    v = wredsum(v);
    if(lane==0) score[t] = v + abias[t];
  }
  __syncthreads();
  if(tid==0){
    float m = fmaxf(fmaxf(score[0],score[1]), fmaxf(score[2],score[3]));
    float e0=__expf(score[0]-m), e1=__expf(score[1]-m), e2=__expf(score[2]-m), e3=__expf(score[3]-m);
    float s = e0+e1+e2+e3;
    wts[0]=e0/s; wts[1]=e1/s; wts[2]=e2/s; wts[3]=e3/s;
  }
  __syncthreads();

  // ---- weighted temporal sum (regs) -> scatter to nodes -> z ----
  for(int idx=tid; idx<NPG*HID; idx+=256) nacc[idx]=0.f;
  __syncthreads();
  const float w1=wts[0], w2=wts[1], w3=wts[2], w4=wts[3];
  #pragma unroll
  for(int mt=0;mt<3;mt++)
    #pragma unroll
    for(int nt=0;nt<2;nt++){
      int ncol = nA + nt*16;
      #pragma unroll
      for(int r=0;r<4;r++){
        float wv = w1*hist[0][mt][nt][r] + w2*hist[1][mt][nt][r]
                 + w3*hist[2][mt][nt][r] + w4*Ocur[mt][nt][r];
        int dn = dstl[mt*16+q*4+r];
        atomicAdd(&nacc[dn*128 + ncol], wv);
      }
    }
  __syncthreads();
  for(int idx=tid; idx<NPG*64; idx+=256){
    int n = idx>>6, cc = idx&63;
    uint hh = ((const uint*)h)[(g*NPG+n)*64 + cc];
    f32x2 zo;
    zo.x = b2f_lo(hh) + nacc[n*128 + 2*cc];
    zo.y = b2f_hi(hh) + nacc[n*128 + 2*cc+1];
    ((f32x2*)z)[(g*NPG+n)*64 + cc] = zo;
  }
}

// ---------------------------------------------------------------------------
// K3: out = z @ w_block + b_block  (bf16x3 MFMA, fp32 in/out)
// ---------------------------------------------------------------------------
__global__ __launch_bounds__(256) void k_final(
    const float* __restrict__ zf, const float* __restrict__ wb, const float* __restrict__ bb,
    float* __restrict__ out)
{
  __shared__ __align__(16) ushort lds[26112];
  ushort* Ah = lds;
  ushort* Al = lds + 8704;
  ushort* Wt = lds + 17408;
  const int tid = threadIdx.x;
  const int lane = tid & 63, wid = tid >> 6;
  const int quad = lane >> 4, ln = lane & 15;
  const int n0 = blockIdx.x * 64;
  const int mrow = wid*16 + ln;
  const f32x4 z4 = {0.f,0.f,0.f,0.f};

  for(int idx=tid; idx<64*128; idx+=256){ int r=idx>>7, k=idx&127;
    float v = zf[(size_t)(n0+r)*128+k]; ushort hi=f2b(v);
    Ah[r*136+k]=hi; Al[r*136+k]=f2b(v-b2f(hi)); }
  __syncthreads();

  for(int half=0; half<2; half++){
    for(int idx=tid; idx<64*128; idx+=256){ int n=idx>>7, k=idx&127;
      Wt[n*136+k]=f2b(wb[k*128 + half*64 + n]); }
    __syncthreads();
    f32x4 a2[4];
    #pragma unroll
    for(int s=0;s<4;s++) a2[s]=z4;
    #pragma unroll
    for(int ks=0;ks<4;ks++){
      const int ko = ks*32 + quad*8;
      bf16x8 ah = *(const bf16x8*)&Ah[mrow*136 + ko];
      bf16x8 al = *(const bf16x8*)&Al[mrow*136 + ko];
      #pragma unroll
      for(int s=0;s<4;s++){
        bf16x8 bf = *(const bf16x8*)&Wt[(s*16+ln)*136 + ko];
        a2[s] = mfma16(ah, bf, a2[s]);
        a2[s] = mfma16(al, bf, a2[s]);
      }
    }
    __syncthreads();
    for(int idx=tid; idx<64*128; idx+=256){ int n=idx>>7, k=idx&127;
      Wt[n*136+k]=f2b_lo(wb[k*128 + half*64 + n]); }
    __syncthreads();
    #pragma unroll
    for(int ks=0;ks<4;ks++){
      const int ko = ks*32 + quad*8;
      bf16x8 ah = *(const bf16x8*)&Ah[mrow*136 + ko];
      #pragma unroll
      for(int s=0;s<4;s++){
        bf16x8 bf = *(const bf16x8*)&Wt[(s*16+ln)*136 + ko];
        a2[s] = mfma16(ah, bf, a2[s]);
      }
    }
    __syncthreads();
    #pragma unroll
    for(int s=0;s<4;s++){
      float bias = bb[half*64 + s*16+ln];
      #pragma unroll
      for(int r=0;r<4;r++)
        out[(size_t)(n0+wid*16+quad*4+r)*128 + half*64 + s*16+ln] = a2[s][r] + bias;
    }
  }
}

// ---------------------------------------------------------------------------
extern "C" void kernel_launch(void* const* d_in, const int* in_sizes, int n_in,
                              void* d_out, int out_size, void* d_ws, size_t ws_size,
                              hipStream_t stream)
{
  (void)in_sizes; (void)n_in; (void)out_size; (void)ws_size;
  const float* x      = (const float*)d_in[0];
  const float* eattr  = (const float*)d_in[1];
  const int*   eidx   = (const int*)d_in[2];
  const int*   lidx   = (const int*)d_in[3];
  const float* wmlp   = (const float*)d_in[5];
  const float* bmlp   = (const float*)d_in[6];
  const float* wu     = (const float*)d_in[7];
  const float* wvv    = (const float*)d_in[8];
  const float* wedge  = (const float*)d_in[9];
  const float* wrel   = (const float*)d_in[10];
  const float* brel   = (const float*)d_in[11];
  const float* wroot  = (const float*)d_in[12];
  const float* aatt   = (const float*)d_in[13];
  const float* abias  = (const float*)d_in[14];
  const float* wgout  = (const float*)d_in[15];
  const float* bgout  = (const float*)d_in[16];
  const float* wblock = (const float*)d_in[17];
  const float* bblock = (const float*)d_in[18];

  char* ws = (char*)d_ws;
  ushort* h  = (ushort*)(ws);                         // bf16 [N,128]
  float*  hu = (float*)(ws + 25165824);               // fp32 [N,128]
  float*  hv = (float*)(ws + 75497472);               // fp32 [N,128]
  float*  zf = (float*)(ws + 125829120);              // fp32 [N,128]

  k_feat <<<NN/64, 256, 0, stream>>>(x, wmlp, bmlp, wu, wvv, h, hu, hv);
  k_graph<<<NGR,   256, 0, stream>>>(hu, hv, h, eattr, eidx, lidx, wedge, wrel, brel,
                                     wroot, aatt, abias, wgout, bgout, zf);
  k_final<<<NN/64, 256, 0, stream>>>(zf, wblock, bblock, (float*)d_out);
}

// Round 7
// 738.584 us; speedup vs baseline: 1.2565x; 1.0114x over previous
//
#include <hip/hip_runtime.h>

#define NGR 4096
#define NPG 24
#define EPG 48
#define LPG 144
#define NITER 4
#define HID 128
#define NN (NGR*NPG)
#define NE (NGR*EPG)
#define NL (NGR*LPG)

typedef unsigned int uint;
typedef unsigned short ushort;
typedef short bf16x8 __attribute__((ext_vector_type(8)));
typedef unsigned short u16x4 __attribute__((ext_vector_type(4)));
typedef float f32x4 __attribute__((ext_vector_type(4)));
typedef float f32x2 __attribute__((ext_vector_type(2)));

__device__ __forceinline__ float b2f(ushort u){ return __uint_as_float(((uint)u)<<16); }
__device__ __forceinline__ ushort f2b(float f){
  uint x = __float_as_uint(f);
  x += 0x7FFFu + ((x>>16)&1u);
  return (ushort)(x>>16);
}
__device__ __forceinline__ float wredsum(float v){
  #pragma unroll
  for(int m=32;m;m>>=1) v += __shfl_xor(v, m, 64);
  return v;
}
__device__ __forceinline__ f32x4 mfma16(bf16x8 a, bf16x8 b, f32x4 c){
  return __builtin_amdgcn_mfma_f32_16x16x32_bf16(a, b, c, 0, 0, 0);
}

// ---------------------------------------------------------------------------
// k_prep: split weights into bf16 hi/lo, transposed [n][k], into ws.
// ushort offsets in P: WmH 0, WmL 12288, WuH 24576, WuL 40960,
//                      WvH 57344, WvL 73728, WbH 90112, WbL 106496
// ---------------------------------------------------------------------------
__global__ __launch_bounds__(256) void k_prep(
    const float* __restrict__ wmlp, const float* __restrict__ wu,
    const float* __restrict__ wv, const float* __restrict__ wb,
    ushort* __restrict__ P)
{
  int id = blockIdx.x*256 + threadIdx.x;
  if(id < 12288){
    int n=id/96, k=id-n*96;
    float v=(k<70)? wmlp[k*128+n] : 0.f;
    ushort hb=f2b(v); P[id]=hb; P[12288+id]=f2b(v-b2f(hb));
  } else if(id < 28672){
    int i=id-12288, n=i>>7, k=i&127;
    float v=wu[k*128+n]; ushort hb=f2b(v);
    P[24576+i]=hb; P[40960+i]=f2b(v-b2f(hb));
  } else if(id < 45056){
    int i=id-28672, n=i>>7, k=i&127;
    float v=wv[k*128+n]; ushort hb=f2b(v);
    P[57344+i]=hb; P[73728+i]=f2b(v-b2f(hb));
  } else if(id < 61440){
    int i=id-45056, n=i>>7, k=i&127;
    float v=wb[k*128+n]; ushort hb=f2b(v);
    P[90112+i]=hb; P[106496+i]=f2b(v-b2f(hb));
  }
}

// ---------------------------------------------------------------------------
// k_fused: one workgroup per graph — GEMMs (bf16x3) + dense-MFMA recursion
// + attention + final GEMM, all in LDS. No intermediate global tensors.
// ---------------------------------------------------------------------------
__global__ __launch_bounds__(256) void k_fused(
  const float* __restrict__ x, const float* __restrict__ ea,
  const int* __restrict__ eidx, const int* __restrict__ lidx,
  const ushort* __restrict__ P,
  const float* __restrict__ bmlp, const float* __restrict__ wedge,
  const float* __restrict__ wrel, const float* __restrict__ brel,
  const float* __restrict__ wroot,
  const float* __restrict__ aatt, const float* __restrict__ abias,
  const float* __restrict__ wgout, const float* __restrict__ bgout,
  const float* __restrict__ bblock,
  float* __restrict__ out)
{
  const int g=blockIdx.x, tid=threadIdx.x, lane=tid&63, wid=tid>>6;
  const int q=lane>>4, ln=lane&15;
  const int E0=g*EPG, L0=g*LPG;
  const int nA = wid*32 + ln;          // this wave owns feature cols [32w,32w+32)

  __shared__ __align__(16) char LB[68128];
  ushort* Hh   = (ushort*)(LB + 0);      // h / z split hi, [32][136]
  ushort* Hl   = (ushort*)(LB + 8704);
  ushort* A_bf = (ushort*)(LB + 17408);  // [48][72]
  // aliased region @24320 (36864 B):
  ushort* xh   = (ushort*)(LB + 24320);  // [32][104]
  ushort* xl   = (ushort*)(LB + 30976);
  uint*   A_u  = (uint*)  (LB + 37632);  // [48][64]
  float*  huL  = (float*) (LB + 24320);  // [24][132]
  float*  hvL  = (float*) (LB + 36992);
  ushort* OUTh = (ushort*)(LB + 24320);  // [128][72]
  ushort* OUTl = (ushort*)(LB + 42752);
  float*  nacc = (float*) (LB + 24320);  // [24][128]
  int*    esrc = (int*)   (LB + 61184);
  int*    edst = (int*)   (LB + 61376);
  ushort* dstl = (ushort*)(LB + 61568);
  float*  eaL  = (float*) (LB + 61696);  // [48][6]
  float*  Pe   = (float*) (LB + 62848);
  float*  Re   = (float*) (LB + 63040);
  float*  xcs  = (float*) (LB + 63232);  // [4][48]
  float*  gsf  = (float*) (LB + 64000);  // [4][128]
  float*  sfull= (float*) (LB + 66048);  // [4][128]
  float*  score= (float*) (LB + 68096);
  float*  wts  = (float*) (LB + 68112);

  const ushort *WmH=P, *WmL=P+12288, *WuH=P+24576, *WuL=P+40960,
               *WvH=P+57344, *WvL=P+73728, *WbH=P+90112, *WbL=P+106496;
  const f32x4 z4 = {0.f,0.f,0.f,0.f};

  // ---- phase 1: indices, ea, x staging, zeros ----
  for(int idx=tid; idx<48*64; idx+=256) A_u[idx]=0u;
  if(tid<48){
    int s=eidx[E0+tid]-g*NPG, d=eidx[NE+E0+tid]-g*NPG;
    esrc[tid]=s; edst[tid]=d; dstl[tid]=(ushort)d; Pe[tid]=0.f; Re[tid]=0.f;
  }
  for(int idx=tid; idx<288; idx+=256) eaL[idx]=ea[(size_t)E0*6+idx];
  for(int idx=tid; idx<24*70; idx+=256){ int r=idx/70,k=idx-r*70;
    float v=x[(size_t)(g*NPG+r)*70+k]; ushort hb=f2b(v);
    xh[r*104+k]=hb; xl[r*104+k]=f2b(v-b2f(hb)); }
  for(int idx=tid; idx<24*34; idx+=256){ int r=idx/34,o=idx-r*34;
    xh[r*104+70+o]=0; xl[r*104+70+o]=0; }
  for(int idx=tid; idx<8*104; idx+=256){ xh[2496+idx]=0; xl[2496+idx]=0; }
  for(int idx=tid; idx<512; idx+=256) sfull[idx]=0.f;
  __syncthreads();
  if(tid<LPG){ int ls=lidx[L0+tid]-E0, ld=lidx[NL+L0+tid]-E0;
    atomicAdd(&A_u[ld*64+ls],1u); }
  __syncthreads();
  for(int idx=tid; idx<48*64; idx+=256){ int i=idx>>6,j=idx&63;
    A_bf[i*72+j]=f2b((float)A_u[idx]); }

  // ---- GEMM1: h = x@wmlp + b  (bf16x3, K=96 padded) ----
  f32x4 hc[2][2];
  #pragma unroll
  for(int mt=0;mt<2;mt++){ hc[mt][0]=z4; hc[mt][1]=z4; }
  #pragma unroll
  for(int kt=0; kt<3; kt++){
    int ko=kt*32+q*8;
    bf16x8 ah0=*(const bf16x8*)&xh[ln*104+ko];
    bf16x8 ah1=*(const bf16x8*)&xh[(16+ln)*104+ko];
    bf16x8 al0=*(const bf16x8*)&xl[ln*104+ko];
    bf16x8 al1=*(const bf16x8*)&xl[(16+ln)*104+ko];
    #pragma unroll
    for(int nt=0;nt<2;nt++){
      int nb=(nA+nt*16)*96+ko;
      bf16x8 bh=*(const bf16x8*)&WmH[nb];
      bf16x8 bl=*(const bf16x8*)&WmL[nb];
      hc[0][nt]=mfma16(ah0,bh,hc[0][nt]);
      hc[0][nt]=mfma16(al0,bh,hc[0][nt]);
      hc[0][nt]=mfma16(ah0,bl,hc[0][nt]);
      hc[1][nt]=mfma16(ah1,bh,hc[1][nt]);
      hc[1][nt]=mfma16(al1,bh,hc[1][nt]);
      hc[1][nt]=mfma16(ah1,bl,hc[1][nt]);
    }
  }
  {
    float bm0=bmlp[nA], bm1=bmlp[nA+16];
    #pragma unroll
    for(int nt=0;nt<2;nt++){ float bb=nt?bm1:bm0; int col=nA+nt*16;
      #pragma unroll
      for(int mt=0;mt<2;mt++)
        #pragma unroll
        for(int r=0;r<4;r++){
          int row=mt*16+q*4+r;
          float hvv=(row<24)? hc[mt][nt][r]+bb : 0.f;
          ushort hb=f2b(hvv);
          Hh[row*136+col]=hb; Hl[row*136+col]=f2b(hvv-b2f(hb));
        }
    }
  }
  __syncthreads();

  // ---- GEMM2/3: hu = h@wu, hv = h@wv -> LDS fp32 (wave-private cols) ----
  #pragma unroll
  for(int w2=0;w2<2;w2++){
    const ushort* WH = w2? WvH:WuH; const ushort* WL = w2? WvL:WuL;
    float* dst = w2? hvL:huL;
    f32x4 c2[2][2];
    c2[0][0]=z4; c2[0][1]=z4; c2[1][0]=z4; c2[1][1]=z4;
    #pragma unroll
    for(int kt=0;kt<4;kt++){
      int ko=kt*32+q*8;
      bf16x8 ah0=*(const bf16x8*)&Hh[ln*136+ko];
      bf16x8 ah1=*(const bf16x8*)&Hh[(16+ln)*136+ko];
      bf16x8 al0=*(const bf16x8*)&Hl[ln*136+ko];
      bf16x8 al1=*(const bf16x8*)&Hl[(16+ln)*136+ko];
      #pragma unroll
      for(int nt=0;nt<2;nt++){
        int nb=(nA+nt*16)*128+ko;
        bf16x8 bh=*(const bf16x8*)&WH[nb];
        bf16x8 bl=*(const bf16x8*)&WL[nb];
        c2[0][nt]=mfma16(ah0,bh,c2[0][nt]);
        c2[0][nt]=mfma16(al0,bh,c2[0][nt]);
        c2[0][nt]=mfma16(ah0,bl,c2[0][nt]);
        c2[1][nt]=mfma16(ah1,bh,c2[1][nt]);
        c2[1][nt]=mfma16(al1,bh,c2[1][nt]);
        c2[1][nt]=mfma16(ah1,bl,c2[1][nt]);
      }
    }
    #pragma unroll
    for(int nt=0;nt<2;nt++)
      #pragma unroll
      for(int mt=0;mt<2;mt++)
        #pragma unroll
        for(int r=0;r<4;r++){
          int row=mt*16+q*4+r;
          if(row<24) dst[row*132 + nA+nt*16]=c2[mt][nt][r];
        }
  }
  // no barrier: e0 below reads only this wave's columns

  // ---- e0 + Pe/Re ----
  const float wrel0=wrel[nA], wrel1=wrel[nA+16];
  const float wroot0=wroot[nA], wroot1=wroot[nA+16];
  float wed0[6],wed1[6];
  #pragma unroll
  for(int k=0;k<6;k++){ wed0[k]=wedge[k*128+nA]; wed1[k]=wedge[k*128+nA+16]; }
  const float brel_f=brel[0];
  f32x4 e0f[3][2];
  #pragma unroll
  for(int mt=0;mt<3;mt++)
    #pragma unroll
    for(int r=0;r<4;r++){
      int m=mt*16+q*4+r;
      int sg=esrc[m], dg=edst[m];
      float v0=huL[sg*132+nA]    + hvL[dg*132+nA];
      float v1=huL[sg*132+nA+16] + hvL[dg*132+nA+16];
      #pragma unroll
      for(int k=0;k<6;k++){ float e=eaL[m*6+k]; v0+=e*wed0[k]; v1+=e*wed1[k]; }
      e0f[mt][0][r]=v0*(1.f/3.f);
      e0f[mt][1][r]=v1*(1.f/3.f);
    }
  #pragma unroll
  for(int mt=0;mt<3;mt++)
    #pragma unroll
    for(int r=0;r<4;r++){
      float pp=e0f[mt][0][r]*wrel0  + e0f[mt][1][r]*wrel1;
      float rr=e0f[mt][0][r]*wroot0 + e0f[mt][1][r]*wroot1;
      #pragma unroll
      for(int msk=1;msk<16;msk<<=1){ pp+=__shfl_xor(pp,msk,64); rr+=__shfl_xor(rr,msk,64); }
      if(ln==0){ atomicAdd(&Pe[mt*16+q*4+r],pp); atomicAdd(&Re[mt*16+q*4+r],rr); }
    }
  __syncthreads();   // all e0 reads done -> hu/hv region reusable; Pe/Re complete

  // ---- out0 = e0 into OUT (split); A-frags; wave0: xcs softmaxes ----
  bf16x8 Af[3][2];
  #pragma unroll
  for(int mt=0;mt<3;mt++){
    Af[mt][0]=*(const bf16x8*)&A_bf[(mt*16+ln)*72+q*8];
    Af[mt][1]=*(const bf16x8*)&A_bf[(mt*16+ln)*72+q*8+32];
  }
  #pragma unroll
  for(int mt=0;mt<3;mt++)
    #pragma unroll
    for(int nt=0;nt<2;nt++){
      u16x4 hh,llv;
      #pragma unroll
      for(int r=0;r<4;r++){ float v=e0f[mt][nt][r]; ushort hb=f2b(v);
        hh[r]=hb; llv[r]=f2b(v-b2f(hb)); }
      int ncol=nA+nt*16;
      *(u16x4*)&OUTh[ncol*72+mt*16+q*4]=hh;
      *(u16x4*)&OUTl[ncol*72+mt*16+q*4]=llv;
    }
  for(int idx=tid; idx<128*16; idx+=256){ int n=idx>>4,kk=48+(idx&15);
    OUTh[n*72+kk]=0; OUTl[n*72+kk]=0; }
  if(wid==0){
    const int arow=(lane<48)?lane:0;
    float pprev=(lane<48)?Pe[lane]:0.f;
    float rprev=(lane<48)?Re[lane]:0.f;
    const float pe_l=pprev, re_l=rprev;
    float rlast=rprev;
    #pragma unroll
    for(int t=1;t<=5;t++){
      float s=0.f, sr=0.f;
      for(int j=0;j<48;j++){
        float a=b2f(A_bf[arow*72+j]);
        float pj=__shfl(pprev,j,64);
        float rj=__shfl(rprev,j,64);
        s+=a*pj; sr+=a*rj;
      }
      s+=pe_l; sr+=re_l;
      if(t>=2){
        float xv = s - pe_l + rlast + brel_f;
        float v=(lane<48)?xv:-3.0e38f;
        float mx=v;
        #pragma unroll
        for(int msk=32;msk;msk>>=1) mx=fmaxf(mx,__shfl_xor(mx,msk,64));
        float e2=(lane<48)?__expf(v-mx):0.f;
        float ss=e2;
        #pragma unroll
        for(int msk=32;msk;msk>>=1) ss+=__shfl_xor(ss,msk,64);
        if(lane<48) xcs[(t-2)*48+lane]=e2/ss;
      }
      pprev=s; rprev=sr; rlast=sr;
    }
  }
  __syncthreads();

  // ---- recursion: out_t = e0 + A @ out_{t-1}  (dense MFMA) ----
  f32x4 Ocur[3][2];
  f32x4 hist[3][3][2];
  #pragma unroll
  for(int t=0;t<NITER;t++){
    bf16x8 Bh[2][2], Bl[2][2];
    #pragma unroll
    for(int nt=0;nt<2;nt++){
      int ncol=nA+nt*16;
      #pragma unroll
      for(int kc=0;kc<2;kc++){
        Bh[nt][kc]=*(const bf16x8*)&OUTh[ncol*72+q*8+kc*32];
        Bl[nt][kc]=*(const bf16x8*)&OUTl[ncol*72+q*8+kc*32];
      }
    }
    __syncthreads();
    #pragma unroll
    for(int mt=0;mt<3;mt++)
      #pragma unroll
      for(int nt=0;nt<2;nt++){
        f32x4 acc=e0f[mt][nt];
        acc=mfma16(Af[mt][0],Bh[nt][0],acc);
        acc=mfma16(Af[mt][1],Bh[nt][1],acc);
        acc=mfma16(Af[mt][0],Bl[nt][0],acc);
        acc=mfma16(Af[mt][1],Bl[nt][1],acc);
        Ocur[mt][nt]=acc;
      }
    float gp0=0.f, gp1=0.f;
    #pragma unroll
    for(int mt=0;mt<3;mt++)
      #pragma unroll
      for(int nt=0;nt<2;nt++){
        u16x4 hh,llv;
        #pragma unroll
        for(int r=0;r<4;r++){ float v=Ocur[mt][nt][r]; ushort hb=f2b(v);
          hh[r]=hb; llv[r]=f2b(v-b2f(hb)); }
        int ncol=nA+nt*16;
        *(u16x4*)&OUTh[ncol*72+mt*16+q*4]=hh;
        *(u16x4*)&OUTl[ncol*72+mt*16+q*4]=llv;
      }
    #pragma unroll
    for(int mt=0;mt<3;mt++)
      #pragma unroll
      for(int r=0;r<4;r++){
        float xcv=xcs[t*48+mt*16+q*4+r];
        gp0+=xcv*Ocur[mt][0][r];
        gp1+=xcv*Ocur[mt][1][r];
      }
    gp0+=__shfl_xor(gp0,16,64); gp0+=__shfl_xor(gp0,32,64);
    gp1+=__shfl_xor(gp1,16,64); gp1+=__shfl_xor(gp1,32,64);
    if(q==0){ gsf[t*128+nA]=gp0; gsf[t*128+nA+16]=gp1; }
    if(t<3){
      #pragma unroll
      for(int mt=0;mt<3;mt++){ hist[t][mt][0]=Ocur[mt][0]; hist[t][mt][1]=Ocur[mt][1]; }
    }
    __syncthreads();
  }

  // ---- cooperative g@wgout partials (each wave: 32-k slab) ----
  {
    float p00=0,p01=0,p10=0,p11=0,p20=0,p21=0,p30=0,p31=0;
    int k0=wid*32;
    for(int kk=0;kk<32;kk++){
      int k=k0+kk;
      f32x2 w=((const f32x2*)wgout)[k*64+lane];
      float g0=gsf[k], g1=gsf[128+k], g2=gsf[256+k], g3=gsf[384+k];
      p00+=g0*w.x; p01+=g0*w.y;
      p10+=g1*w.x; p11+=g1*w.y;
      p20+=g2*w.x; p21+=g2*w.y;
      p30+=g3*w.x; p31+=g3*w.y;
    }
    atomicAdd(&sfull[2*lane],p00);     atomicAdd(&sfull[2*lane+1],p01);
    atomicAdd(&sfull[128+2*lane],p10); atomicAdd(&sfull[128+2*lane+1],p11);
    atomicAdd(&sfull[256+2*lane],p20); atomicAdd(&sfull[256+2*lane+1],p21);
    atomicAdd(&sfull[384+2*lane],p30); atomicAdd(&sfull[384+2*lane+1],p31);
  }
  __syncthreads();
  {
    int t=wid;
    float s0=sfull[t*128+2*lane]  +bgout[2*lane];
    float s1=sfull[t*128+2*lane+1]+bgout[2*lane+1];
    float v=tanhf(s0)*aatt[(2*lane)*4+t]+tanhf(s1)*aatt[(2*lane+1)*4+t];
    v=wredsum(v);
    if(lane==0) score[t]=v+abias[t];
  }
  for(int idx=tid; idx<24*128; idx+=256) nacc[idx]=0.f;   // OUT dead
  __syncthreads();
  if(tid==0){
    float m=fmaxf(fmaxf(score[0],score[1]),fmaxf(score[2],score[3]));
    float e0=__expf(score[0]-m), e1=__expf(score[1]-m),
          e2=__expf(score[2]-m), e3=__expf(score[3]-m);
    float s=e0+e1+e2+e3;
    wts[0]=e0/s; wts[1]=e1/s; wts[2]=e2/s; wts[3]=e3/s;
  }
  __syncthreads();

  // ---- weighted temporal sum -> node scatter ----
  {
    const float w1=wts[0],w2=wts[1],w3=wts[2],w4=wts[3];
    #pragma unroll
    for(int mt=0;mt<3;mt++)
      #pragma unroll
      for(int nt=0;nt<2;nt++){
        int ncol=nA+nt*16;
        #pragma unroll
        for(int r=0;r<4;r++){
          float wv=w1*hist[0][mt][nt][r]+w2*hist[1][mt][nt][r]
                  +w3*hist[2][mt][nt][r]+w4*Ocur[mt][nt][r];
          int dn=dstl[mt*16+q*4+r];
          atomicAdd(&nacc[dn*128+ncol],wv);
        }
      }
  }
  __syncthreads();
  // ---- z = h + nacc, in-place split into Hh/Hl ----
  for(int idx=tid; idx<24*128; idx+=256){
    int n=idx>>7, k=idx&127;
    float zv=b2f(Hh[n*136+k])+b2f(Hl[n*136+k])+nacc[idx];
    ushort hb=f2b(zv);
    Hh[n*136+k]=hb; Hl[n*136+k]=f2b(zv-b2f(hb));
  }
  __syncthreads();
  // ---- GEMM4: out = z@wblock + b ----
  f32x4 c4[2][2];
  c4[0][0]=z4; c4[0][1]=z4; c4[1][0]=z4; c4[1][1]=z4;
  #pragma unroll
  for(int kt=0;kt<4;kt++){
    int ko=kt*32+q*8;
    bf16x8 ah0=*(const bf16x8*)&Hh[ln*136+ko];
    bf16x8 ah1=*(const bf16x8*)&Hh[(16+ln)*136+ko];
    bf16x8 al0=*(const bf16x8*)&Hl[ln*136+ko];
    bf16x8 al1=*(const bf16x8*)&Hl[(16+ln)*136+ko];
    #pragma unroll
    for(int nt=0;nt<2;nt++){
      int nb=(nA+nt*16)*128+ko;
      bf16x8 bh=*(const bf16x8*)&WbH[nb];
      bf16x8 bl=*(const bf16x8*)&WbL[nb];
      c4[0][nt]=mfma16(ah0,bh,c4[0][nt]);
      c4[0][nt]=mfma16(al0,bh,c4[0][nt]);
      c4[0][nt]=mfma16(ah0,bl,c4[0][nt]);
      c4[1][nt]=mfma16(ah1,bh,c4[1][nt]);
      c4[1][nt]=mfma16(al1,bh,c4[1][nt]);
      c4[1][nt]=mfma16(ah1,bl,c4[1][nt]);
    }
  }
  {
    float bb0=bblock[nA], bb1=bblock[nA+16];
    #pragma unroll
    for(int nt=0;nt<2;nt++){ float bbx=nt?bb1:bb0; int col=nA+nt*16;
      #pragma unroll
      for(int mt=0;mt<2;mt++)
        #pragma unroll
        for(int r=0;r<4;r++){
          int row=mt*16+q*4+r;
          if(row<24) out[(size_t)(g*NPG+row)*128+col]=c4[mt][nt][r]+bbx;
        }
    }
  }
}

// ---------------------------------------------------------------------------
extern "C" void kernel_launch(void* const* d_in, const int* in_sizes, int n_in,
                              void* d_out, int out_size, void* d_ws, size_t ws_size,
                              hipStream_t stream)
{
  (void)in_sizes; (void)n_in; (void)out_size; (void)ws_size;
  const float* x      = (const float*)d_in[0];
  const float* eattr  = (const float*)d_in[1];
  const int*   eidx   = (const int*)d_in[2];
  const int*   lidx   = (const int*)d_in[3];
  const float* wmlp   = (const float*)d_in[5];
  const float* bmlp   = (const float*)d_in[6];
  const float* wu     = (const float*)d_in[7];
  const float* wvv    = (const float*)d_in[8];
  const float* wedge  = (const float*)d_in[9];
  const float* wrel   = (const float*)d_in[10];
  const float* brel   = (const float*)d_in[11];
  const float* wroot  = (const float*)d_in[12];
  const float* aatt   = (const float*)d_in[13];
  const float* abias  = (const float*)d_in[14];
  const float* wgout  = (const float*)d_in[15];
  const float* bgout  = (const float*)d_in[16];
  const float* wblock = (const float*)d_in[17];
  const float* bblock = (const float*)d_in[18];

  ushort* P = (ushort*)d_ws;   // 245,760 B of pre-split weights

  k_prep <<<240, 256, 0, stream>>>(wmlp, wu, wvv, wblock, P);
  k_fused<<<NGR, 256, 0, stream>>>(x, eattr, eidx, lidx, P,
                                   bmlp, wedge, wrel, brel, wroot,
                                   aatt, abias, wgout, bgout, bblock,
                                   (float*)d_out);
}